// Round 5
// baseline (722.441 us; speedup 1.0000x reference)
//
#include <hip/hip_runtime.h>
#include <hip/hip_cooperative_groups.h>
#include <cstdint>
#include <cstddef>

namespace cg = cooperative_groups;

// N=50000 nodes, E=500000 edges, EMB=64, PRED_IN=276.
// Padded-K bf16 MFMA layout (K=288 = 9*32):
//   pk   0.. 63 : q_emb     (k 0..63)
//   pk  64..127 : edge_attr (k 138..201)
//   pk 128..207 : h_e[src]  (k 64..137) + 6 pad
//   pk 208..287 : h_e[dst]  (k 202..275) + 6 pad
// h_e stored bf16 [N][80]: x(64) topic(2) f1(2) f2(2) r1(2) r2(2) pad(6).
//
// Round-7: prep fused into ONE cooperative kernel (9 phases, grid.sync between).
// Rationale: prep has been constant ~450us across two prep strategies while
// every per-kernel model sums to <120us; fusing removes 7 dispatch boundaries
// and forces the true prep cost into one profiled dispatch. k_gemm reverted to
// the best-measured R3 variant (depth-2, 4-wave, 77824B LDS, ~102us).

typedef __bf16 bf16x8 __attribute__((ext_vector_type(8)));
typedef float f32x4 __attribute__((ext_vector_type(4)));

__device__ __forceinline__ unsigned int f2bf1(float f) {   // RNE fp32->bf16
    unsigned int u = __float_as_uint(f);
    return (u + 0x7fffu + ((u >> 16) & 1u)) >> 16;
}
__device__ __forceinline__ unsigned int pk2(float a, float b) {
    return f2bf1(a) | (f2bf1(b) << 16);
}
__device__ __forceinline__ bf16x8 cvt8v(float4 a, float4 b) {
    bf16x8 r;
    r[0] = (__bf16)a.x; r[1] = (__bf16)a.y; r[2] = (__bf16)a.z; r[3] = (__bf16)a.w;
    r[4] = (__bf16)b.x; r[5] = (__bf16)b.y; r[6] = (__bf16)b.z; r[7] = (__bf16)b.w;
    return r;
}

#define GL16(gp, lp)                                                        \
    __builtin_amdgcn_global_load_lds(                                       \
        (const __attribute__((address_space(1))) void*)(gp),                \
        (__attribute__((address_space(3))) void*)(lp), 16, 0, 0)

// ---------------------------------------------------------------------------
// Fused prep (cooperative). 256 blocks x 1024 threads, grid-stride phases.
// ---------------------------------------------------------------------------

__device__ __forceinline__ void round_body(int gtid, int gsz, int N, int E,
                                           const int* __restrict__ off_f,
                                           const int* __restrict__ csr_f,
                                           const int* __restrict__ off_r,
                                           const int* __restrict__ csr_r,
                                           const float2* __restrict__ hf,
                                           const float2* __restrict__ hr,
                                           float2* __restrict__ fo,
                                           float2* __restrict__ ro) {
    for (int gid = gtid; gid < 2 * N; gid += gsz) {
        const bool rev = gid >= N;
        const int n = rev ? gid - N : gid;
        const int* __restrict__ off = rev ? off_r : off_f;
        const int* __restrict__ csr = rev ? csr_r : csr_f;
        const float2* __restrict__ h = rev ? hr : hf;
        int b = off[n], e = (n + 1 < N) ? off[n + 1] : E;
        float sx = 0.f, sy = 0.f;
        for (int j = b; j < e; ++j) { float2 t = h[csr[j]]; sx += t.x; sy += t.y; }
        float inv = 1.0f / (float)max(e - b, 1);
        (rev ? ro : fo)[n] = make_float2(sx * inv, sy * inv);
    }
}

__launch_bounds__(1024)
__global__ void k_prep(const int* __restrict__ idx, int E, int N,
                       int* __restrict__ flag,
                       const float* __restrict__ W1, unsigned short* __restrict__ W1T,
                       int* __restrict__ src_i, int* __restrict__ dst_i,
                       int* __restrict__ cnt_dst, int* __restrict__ cnt_src,
                       unsigned short* __restrict__ pos_f, unsigned short* __restrict__ pos_r,
                       int* __restrict__ off_f, int* __restrict__ off_r,
                       int* __restrict__ csr_f, int* __restrict__ csr_r,
                       int* __restrict__ totf, int* __restrict__ totr,
                       const float* __restrict__ topic, const float* __restrict__ x,
                       const float* __restrict__ nte,
                       float* __restrict__ f1, float* __restrict__ f2,
                       float* __restrict__ r1, float* __restrict__ r2,
                       unsigned short* __restrict__ he)
{
    cg::grid_group grid = cg::this_grid();
    __shared__ int wp[16];

    const int t = threadIdx.x;           // 0..1023
    const int b = blockIdx.x;
    const int nb = gridDim.x;            // 256
    const int gsz = nb * 1024;
    const int gtid = b * 1024 + t;
    const int lane = t & 63;
    const int wid = t >> 6;

    // ---- P0: detect int64-vs-int32 layout + build W1T table ----
    for (int e = gtid; e < E; e += gsz) {
        bool nz = idx[2 * e + 1] != 0;
        unsigned long long m = __ballot(nz);
        if (m != 0ull && lane == 0) atomicOr(flag, 1);
    }
    // W1T linear-LDS layout: ushort index i = ((ct*9+ks)*64 + l)*8 + j holds
    // W1[pk-mapped k][col], col = ct*16+(l&15), pk = ks*32+(l>>4)*8+j.
    for (int i = gtid; i < 64 * 288; i += gsz) {
        int j = i & 7;
        int l = (i >> 3) & 63;
        int t36 = i >> 9;
        int ks = t36 % 9, ct = t36 / 9;
        int col = ct * 16 + (l & 15);
        int pk = ks * 32 + (l >> 4) * 8 + j;
        int k = 0; bool valid = true;
        if (pk < 64)       { k = pk; }
        else if (pk < 128) { k = 138 + (pk - 64); }
        else if (pk < 208) { int jj = pk - 128; k = 64 + jj;  valid = jj < 74; }
        else               { int jj = pk - 208; k = 202 + jj; valid = jj < 74; }
        float v = valid ? W1[k * 64 + col] : 0.f;
        W1T[i] = (unsigned short)f2bf1(v);
    }
    grid.sync();

    // ---- P1: unpack indices + CSR slot assignment (2 int atomics/edge) ----
    {
        const int fl = *flag;
        for (int e = gtid; e < E; e += gsz) {
            int s, d;
            if (fl) { s = idx[e];     d = idx[E + e]; }
            else    { s = idx[2 * e]; d = idx[2 * E + 2 * e]; }
            src_i[e] = s; dst_i[e] = d;
            pos_f[e] = (unsigned short)atomicAdd(&cnt_dst[d], 1);
            pos_r[e] = (unsigned short)atomicAdd(&cnt_src[s], 1);
        }
    }
    grid.sync();

    // ---- P2..P4: parallel exclusive scan of cnt -> off (both arrays) ----
    // Per block: chunk of C elements; threads 0..255 handle cnt_dst, 256..511
    // handle cnt_src. pref (register) survives grid.sync to P4.
    const int C = (N + nb - 1) / nb;     // 196 for N=50000, nb=256 (C <= 256)
    const int grp = t >> 8;              // 0: f/dst, 1: r/src, >=2 idle
    const int u = t & 255;
    int pref = 0;
    {
        int i = b * C + u;
        int val = 0;
        if (grp < 2 && u < C && i < N) val = (grp == 0 ? cnt_dst : cnt_src)[i];
        int incl = val;
        for (int ofs = 1; ofs < 64; ofs <<= 1) {
            int uu = __shfl_up(incl, ofs);
            if (lane >= ofs) incl += uu;
        }
        if (lane == 63) wp[wid] = incl;
        __syncthreads();
        int wofs = 0;
        if (grp < 2) {
            int base = grp * 4, wi = wid - base;
            for (int k = 0; k < wi; ++k) wofs += wp[base + k];
        }
        pref = wofs + incl - val;        // exclusive within block
        if (grp < 2 && u == 255) (grp == 0 ? totf : totr)[b] = wofs + incl;
    }
    grid.sync();

    // P3: block 0 scans the per-block totals in place (exclusive).
    if (b == 0) {
        int val = 0;
        if (grp < 2 && u < nb) val = (grp == 0 ? totf : totr)[u];
        int incl = val;
        for (int ofs = 1; ofs < 64; ofs <<= 1) {
            int uu = __shfl_up(incl, ofs);
            if (lane >= ofs) incl += uu;
        }
        __syncthreads();                 // wp reuse hazard guard
        if (lane == 63) wp[wid] = incl;
        __syncthreads();
        int wofs = 0;
        if (grp < 2) {
            int base = grp * 4, wi = wid - base;
            for (int k = 0; k < wi; ++k) wofs += wp[base + k];
        }
        if (grp < 2 && u < nb) (grp == 0 ? totf : totr)[u] = wofs + incl - val;
    }
    grid.sync();

    // P4: emit off arrays.
    {
        int i = b * C + u;
        if (grp == 0 && u < C && i < N) off_f[i] = totf[b] + pref;
        if (grp == 1 && u < C && i < N) off_r[i] = totr[b] + pref;
    }
    grid.sync();

    // ---- P5: fill CSR ----
    for (int e = gtid; e < E; e += gsz) {
        int s = src_i[e], d = dst_i[e];
        csr_f[off_f[d] + pos_f[e]] = s;
        csr_r[off_r[s] + pos_r[e]] = d;
    }
    grid.sync();

    // ---- P6/P7: two DDE rounds (atomic-free segment means) ----
    round_body(gtid, gsz, N, E, off_f, csr_f, off_r, csr_r,
               (const float2*)topic, (const float2*)topic, (float2*)f1, (float2*)r1);
    grid.sync();
    round_body(gtid, gsz, N, E, off_f, csr_f, off_r, csr_r,
               (const float2*)f1, (const float2*)r1, (float2*)f2, (float2*)r2);
    grid.sync();

    // ---- P8: build bf16 h_e rows ----
    for (int n = gtid; n < N; n += gsz) {
        const float4* xr = (const float4*)(x + (size_t)n * 64);
        float4 v[16];
        bool allz = true;
#pragma unroll
        for (int i = 0; i < 16; ++i) {
            v[i] = xr[i];
            allz = allz && (v[i].x == 0.f && v[i].y == 0.f && v[i].z == 0.f && v[i].w == 0.f);
        }
        const float4* nr = (const float4*)nte;
        unsigned int row[40];
#pragma unroll
        for (int i = 0; i < 16; ++i) {
            float4 s = allz ? nr[i] : v[i];
            row[2 * i]     = pk2(s.x, s.y);
            row[2 * i + 1] = pk2(s.z, s.w);
        }
        row[32] = pk2(topic[2 * n], topic[2 * n + 1]);
        row[33] = pk2(f1[2 * n], f1[2 * n + 1]);
        row[34] = pk2(f2[2 * n], f2[2 * n + 1]);
        row[35] = pk2(r1[2 * n], r1[2 * n + 1]);
        row[36] = pk2(r2[2 * n], r2[2 * n + 1]);
        row[37] = 0u; row[38] = 0u; row[39] = 0u;
        uint4* dst = (uint4*)(he + (size_t)n * 80);
#pragma unroll
        for (int i = 0; i < 10; ++i) dst[i] = ((const uint4*)row)[i];
    }
}

// ---------------------------------------------------------------------------
// MFMA edge-MLP, async pipeline (R3 best-measured variant, ~102us).
// 256 threads = 4 waves/block, 16 edges (1 M-tile) per wave per iteration.
// LDS 77,824 B/block: [W1T 36,864][wave w: buf0/buf1 5,120 each at 36864+w*10240]
//   -> 2 blocks/CU -> 8 waves/CU = 2 waves/SIMD.
// he buffers: chunk-plane layout, plane p (0..19) at p*256 + edge*16:
//   planes 0..9 = he[src] chunks, planes 10..19 = he[dst] chunks.
// Steady loop per wave (no barriers, no vmcnt(0)):
//   issue 8 q/ea reg loads (T+NW) + 5 global_load_lds (T+NW, addrs from siA
//   loaded 2 iters ago) + 2 idx loads (T+3NW); s_waitcnt vmcnt(15); compute T.
// ---------------------------------------------------------------------------

__launch_bounds__(256, 2)
__global__ void k_gemm(const float* __restrict__ q_emb,
                       const float* __restrict__ edge_attr,
                       const unsigned short* __restrict__ he,
                       const unsigned short* __restrict__ W1Tg,
                       const int* __restrict__ src_i, const int* __restrict__ dst_i,
                       const float* __restrict__ b1, const float* __restrict__ W2,
                       const float* __restrict__ b2, float* __restrict__ out, int E)
{
    __shared__ __align__(64) char smem[77824];
    const int tid = threadIdx.x;
    const int w = tid >> 6, l = tid & 63, c = l & 15, q = l >> 4;
    const int NW = gridDim.x * 4;
    const int gw = blockIdx.x * 4 + w;
    const int ntiles = E / 16;          // E % 16 == 0

    // W1T -> LDS (36 KB linear copy; 36 x 1KB DMA, 9 per wave)
#pragma unroll
    for (int jj = 0; jj < 9; ++jj) {
        int j = w * 9 + jj;
        GL16((const char*)W1Tg + j * 1024 + l * 16, smem + j * 1024);
    }

    char* buf0 = smem + 36864 + w * 10240;
    char* buf1 = buf0 + 5120;

    int T = gw;
    // prologue: stage tile T into buf0, prefetch q/ea(T) regs, idx depth-2
    {
        int e0 = T * 16 + c;
        int s0 = src_i[e0], d0 = dst_i[e0];
#pragma unroll
        for (int j = 0; j < 5; ++j) {
            int ch = j * 4 + q;
            int node = ch < 10 ? s0 : d0;
            int chunk = ch < 10 ? ch : ch - 10;
            GL16((const char*)he + (size_t)node * 160 + chunk * 16, buf0 + j * 1024);
        }
    }
    const float* qr0 = q_emb     + (size_t)(T * 16 + c) * 64 + q * 8;
    const float* ar0 = edge_attr + (size_t)(T * 16 + c) * 64 + q * 8;
    float4 qc0 = *(const float4*)qr0,        qc1 = *(const float4*)(qr0 + 4);
    float4 qc2 = *(const float4*)(qr0 + 32), qc3 = *(const float4*)(qr0 + 36);
    float4 ec0 = *(const float4*)ar0,        ec1 = *(const float4*)(ar0 + 4);
    float4 ec2 = *(const float4*)(ar0 + 32), ec3 = *(const float4*)(ar0 + 36);
    int siA, diA, siB, diB;
    {
        int eA = min(T + NW, ntiles - 1) * 16 + c;
        int eB = min(T + 2 * NW, ntiles - 1) * 16 + c;
        siA = src_i[eA]; diA = dst_i[eA];
        siB = src_i[eB]; diB = dst_i[eB];
    }
    float b1v[4], w2v[4];
#pragma unroll
    for (int ct = 0; ct < 4; ++ct) { b1v[ct] = b1[ct * 16 + c]; w2v[ct] = W2[ct * 16 + c]; }
    const float bb = b2[0];
    __syncthreads();   // drains all prologue DMA + makes W1T visible to all waves

    int cur = 0;
    while (T < ntiles) {
        const int Tn = T + NW;
        const bool more = Tn < ntiles;
        float4 qn0, qn1, qn2, qn3, en0, en1, en2, en3;
        int siC = siB, diC = diB;
        char* sbuf = cur ? buf0 : buf1;   // staging target
        char* cbuf = cur ? buf1 : buf0;   // compute source

        if (more) {
            const float* qr = q_emb     + (size_t)(Tn * 16 + c) * 64 + q * 8;
            const float* ar = edge_attr + (size_t)(Tn * 16 + c) * 64 + q * 8;
            qn0 = *(const float4*)qr;        qn1 = *(const float4*)(qr + 4);
            qn2 = *(const float4*)(qr + 32); qn3 = *(const float4*)(qr + 36);
            en0 = *(const float4*)ar;        en1 = *(const float4*)(ar + 4);
            en2 = *(const float4*)(ar + 32); en3 = *(const float4*)(ar + 36);
#pragma unroll
            for (int j = 0; j < 5; ++j) {
                int ch = j * 4 + q;
                int node = ch < 10 ? siA : diA;
                int chunk = ch < 10 ? ch : ch - 10;
                GL16((const char*)he + (size_t)node * 160 + chunk * 16, sbuf + j * 1024);
            }
            int eC = min(T + 3 * NW, ntiles - 1) * 16 + c;
            siC = src_i[eC]; diC = dst_i[eC];
            asm volatile("s_waitcnt vmcnt(15)" ::: "memory");
        } else {
            qn0 = qc0; qn1 = qc1; qn2 = qc2; qn3 = qc3;
            en0 = ec0; en1 = ec1; en2 = ec2; en3 = ec3;
            asm volatile("s_waitcnt vmcnt(0)" ::: "memory");
        }
        __builtin_amdgcn_sched_barrier(0);

        // ---- compute tile T ----
        f32x4 acc0 = {}, acc1 = {}, acc2 = {}, acc3 = {};
        const char* wbase = smem + (size_t)l * 16;
#define BF(ct, ks) (*(const bf16x8*)(wbase + (ct) * 9216 + (ks) * 1024))
#define HEF(pl) (*(const bf16x8*)(cbuf + (pl) * 256 + c * 16))
#define KST(ks, A)                                                                 \
        {                                                                          \
            bf16x8 a_ = (A);                                                       \
            acc0 = __builtin_amdgcn_mfma_f32_16x16x32_bf16(a_, BF(0, ks), acc0, 0, 0, 0); \
            acc1 = __builtin_amdgcn_mfma_f32_16x16x32_bf16(a_, BF(1, ks), acc1, 0, 0, 0); \
            acc2 = __builtin_amdgcn_mfma_f32_16x16x32_bf16(a_, BF(2, ks), acc2, 0, 0, 0); \
            acc3 = __builtin_amdgcn_mfma_f32_16x16x32_bf16(a_, BF(3, ks), acc3, 0, 0, 0); \
        }
        KST(0, cvt8v(qc0, qc1))
        KST(1, cvt8v(qc2, qc3))
        KST(2, cvt8v(ec0, ec1))
        KST(3, cvt8v(ec2, ec3))
        KST(4, HEF(q))            // hs chunks q
        KST(5, HEF(q + 4))        // hs chunks q+4
        KST(6, HEF(q + 8))        // q<2: hs 8,9 ; q>=2: hd 0,1 (planes contiguous)
        KST(7, HEF(q + 12))       // hd chunks 2..5
        KST(8, HEF(q + 16))       // hd chunks 6..9
#undef KST
#undef HEF
#undef BF

        float pr[4];
#pragma unroll
        for (int r = 0; r < 4; ++r) {
            float h0 = fmaxf(acc0[r] + b1v[0], 0.f);
            float h1 = fmaxf(acc1[r] + b1v[1], 0.f);
            float h2 = fmaxf(acc2[r] + b1v[2], 0.f);
            float h3 = fmaxf(acc3[r] + b1v[3], 0.f);
            float p = fmaf(h0, w2v[0], fmaf(h1, w2v[1], fmaf(h2, w2v[2], h3 * w2v[3])));
            p += __shfl_xor(p, 1);
            p += __shfl_xor(p, 2);
            p += __shfl_xor(p, 4);
            p += __shfl_xor(p, 8);
            pr[r] = p;
        }
        if (c == 0) {
            *(float4*)&out[T * 16 + q * 4] =
                make_float4(pr[0] + bb, pr[1] + bb, pr[2] + bb, pr[3] + bb);
        }

        qc0 = qn0; qc1 = qn1; qc2 = qn2; qc3 = qn3;
        ec0 = en0; ec1 = en1; ec2 = en2; ec3 = en3;
        siA = siB; diA = diB; siB = siC; diB = diC;
        T = Tn; cur ^= 1;
    }
}

// ---------------------------------------------------------------------------
// Launch
// ---------------------------------------------------------------------------

extern "C" void kernel_launch(void* const* d_in, const int* in_sizes, int n_in,
                              void* d_out, int out_size, void* d_ws, size_t ws_size,
                              hipStream_t stream)
{
    const float* x         = (const float*)d_in[0];
    const int*   eidx      = (const int*)  d_in[1];
    const float* edge_attr = (const float*)d_in[2];
    const float* topic     = (const float*)d_in[3];
    const float* q_emb     = (const float*)d_in[4];
    const float* nte       = (const float*)d_in[5];
    const float* W1        = (const float*)d_in[6];
    const float* b1        = (const float*)d_in[7];
    const float* W2        = (const float*)d_in[8];
    const float* b2        = (const float*)d_in[9];
    float* out = (float*)d_out;

    const int E = out_size;             // 500000
    const int N = in_sizes[0] / 64;     // 50000

    char* ws = (char*)d_ws;
    int* flag  = (int*)ws;
    int* src_i = (int*)(ws + 16);
    int* dst_i = src_i + E;
    int* off_f = dst_i + E;
    int* off_r = off_f + N;
    float* fblk = (float*)(off_r + N);
    float* f1 = fblk;
    float* f2 = fblk + 2 * (size_t)N;
    float* r1 = fblk + 4 * (size_t)N;
    float* r2 = fblk + 6 * (size_t)N;
    int* cnt_dst = (int*)f1;            // dead before f1 is written (P6)
    int* cnt_src = cnt_dst + N;
    int* totf = (int*)r2;               // dead before r2 is written (P7)
    int* totr = totf + 256;
    char* heblk = (char*)(fblk + 8 * (size_t)N);
    unsigned short* pos_f = (unsigned short*)heblk;          // dead before he is written (P8)
    unsigned short* pos_r = pos_f + E;
    int* csr_f = (int*)(pos_r + E);
    int* csr_r = csr_f + E;
    unsigned short* he = (unsigned short*)heblk;
    size_t he_bytes = (size_t)N * 160;
    size_t trans_bytes = (size_t)E * 12;
    size_t heblk_bytes = he_bytes > trans_bytes ? he_bytes : trans_bytes;
    unsigned short* W1T = (unsigned short*)(heblk + heblk_bytes);

    size_t needed = 16 + (size_t)8 * E + (size_t)8 * N + (size_t)32 * N + heblk_bytes + 64 * 288 * 2;
    if (ws_size < needed) return;

    hipMemsetAsync(flag, 0, 16, stream);
    hipMemsetAsync(cnt_dst, 0, (size_t)8 * N, stream);   // both cnt arrays

    int Ei = E, Ni = N;
    void* args[] = {
        (void*)&eidx, (void*)&Ei, (void*)&Ni, (void*)&flag,
        (void*)&W1, (void*)&W1T,
        (void*)&src_i, (void*)&dst_i, (void*)&cnt_dst, (void*)&cnt_src,
        (void*)&pos_f, (void*)&pos_r, (void*)&off_f, (void*)&off_r,
        (void*)&csr_f, (void*)&csr_r, (void*)&totf, (void*)&totr,
        (void*)&topic, (void*)&x, (void*)&nte,
        (void*)&f1, (void*)&f2, (void*)&r1, (void*)&r2, (void*)&he
    };
    hipLaunchCooperativeKernel((const void*)k_prep, dim3(256), dim3(1024),
                               args, 0, stream);

    k_gemm<<<512, 256, 0, stream>>>(q_emb, edge_attr, he, W1T,
                                    src_i, dst_i, b1, W2, b2, out, E);
}